// Round 1
// baseline (191.254 us; speedup 1.0000x reference)
//
#include <hip/hip_runtime.h>

#define A_N   256
#define T_TOK 32
#define B_N   256
#define V_FRM 16
#define D_DIM 512
#define TAUF  100.0f

typedef _Float16 half8 __attribute__((ext_vector_type(8)));
typedef float    floatx4 __attribute__((ext_vector_type(4)));

// async global->LDS, 16B/lane. LDS dest = wave-uniform base + lane*16.
__device__ __forceinline__ void async_copy16(const void* g, void* l) {
#if __has_builtin(__builtin_amdgcn_global_load_lds)
  __builtin_amdgcn_global_load_lds((const __attribute__((address_space(1))) void*)g,
                                   (__attribute__((address_space(3))) void*)l, 16, 0, 0);
#else
  const int lane = threadIdx.x & 63;
  *(float4*)((char*)l + lane * 16) = *(const float4*)g;
#endif
}

// ---------------- Kernel 1: L2-normalize rows + cast to fp16 ----------------
// H layout: rows 0..8191 = text (a*32+t), rows 8192..12287 = video (b*16+v), 512 halves each.
__global__ __launch_bounds__(256) void norm_cast_kernel(
    const float* __restrict__ text, const float* __restrict__ video,
    _Float16* __restrict__ H)
{
  const int w    = threadIdx.x >> 6;
  const int lane = threadIdx.x & 63;
  const int rid  = blockIdx.x * 4 + w;   // 0..12287
  const float* src = (rid < A_N * T_TOK)
                       ? (text + (size_t)rid * D_DIM)
                       : (video + (size_t)(rid - A_N * T_TOK) * D_DIM);
  float4 v0 = *(const float4*)(src + lane * 8);
  float4 v1 = *(const float4*)(src + lane * 8 + 4);
  float ss = v0.x*v0.x + v0.y*v0.y + v0.z*v0.z + v0.w*v0.w
           + v1.x*v1.x + v1.y*v1.y + v1.z*v1.z + v1.w*v1.w;
#pragma unroll
  for (int d = 1; d < 64; d <<= 1) ss += __shfl_xor(ss, d);
  const float s = 1.0f / fmaxf(sqrtf(ss), 1e-6f);
  half8 hv;
  hv[0] = (_Float16)(v0.x * s); hv[1] = (_Float16)(v0.y * s);
  hv[2] = (_Float16)(v0.z * s); hv[3] = (_Float16)(v0.w * s);
  hv[4] = (_Float16)(v1.x * s); hv[5] = (_Float16)(v1.y * s);
  hv[6] = (_Float16)(v1.z * s); hv[7] = (_Float16)(v1.w * s);
  *(half8*)(H + (size_t)rid * D_DIM + lane * 8) = hv;
}

// ---------------- Kernel 2: fused GEMM + dual softmax pooling ----------------
// Block tile 128x128 (4 a's x 8 b's). 4 waves in 2x2, 64x64 per wave.
// Wave owns 8 complete (a,b) 32x16 pair tiles -> in-register epilogue.
__global__ __launch_bounds__(256, 2) void score_kernel(
    const _Float16* __restrict__ H, const float* __restrict__ tmask,
    float* __restrict__ out)
{
  __shared__ __align__(16) _Float16 sA[128 * 32];  // [row][k], stride 32 halves (64B)
  __shared__ __align__(16) _Float16 sB[128 * 32];
  __shared__ float lmask[128];

  const int tid  = threadIdx.x;
  const int w    = tid >> 6;
  const int lane = tid & 63;
  const int bn   = blockIdx.x;       // 0..31 -> 8 b's
  const int bm   = blockIdx.y;       // 0..63 -> 4 a's
  const int mBase = bm * 128;        // global M row = a*32+t
  const int nBase = bn * 128;        // global N row = b*16+v

  if (tid < 128) lmask[tid] = tmask[mBase + tid];

  const char* gA = (const char*)(H + (size_t)mBase * D_DIM);
  const char* gB = (const char*)(H + (size_t)(A_N * T_TOK + nBase) * D_DIM);
  // within a 16-row staging group: 4 lanes/row (64B), lane -> row/col-bytes
  const int rowoff = (lane >> 2) * 1024 + (lane & 3) * 16;

  floatx4 acc[4][4];
#pragma unroll
  for (int i = 0; i < 4; ++i)
#pragma unroll
    for (int j = 0; j < 4; ++j) acc[i][j] = {0.f, 0.f, 0.f, 0.f};

  const int colL = lane & 15;   // v within pair / MFMA col
  const int quad = lane >> 4;
  const int aRowBase = (w >> 1) * 64;
  const int bRowBase = (w & 1) * 64;

  for (int kt = 0; kt < 16; ++kt) {
    const int kb = kt * 64;  // K-chunk byte offset within row
#pragma unroll
    for (int is = 0; is < 2; ++is) {
      const int rbase = w * 32 + is * 16;
      async_copy16(gA + (size_t)rbase * 1024 + rowoff + kb, (char*)sA + rbase * 64);
      async_copy16(gB + (size_t)rbase * 1024 + rowoff + kb, (char*)sB + rbase * 64);
    }
    __syncthreads();   // drains vmcnt(0) before barrier

    half8 aF[4], bF[4];
#pragma unroll
    for (int i = 0; i < 4; ++i)
      aF[i] = *(const half8*)&sA[(aRowBase + i * 16 + colL) * 32 + quad * 8];
#pragma unroll
    for (int j = 0; j < 4; ++j)
      bF[j] = *(const half8*)&sB[(bRowBase + j * 16 + colL) * 32 + quad * 8];
#pragma unroll
    for (int i = 0; i < 4; ++i)
#pragma unroll
      for (int j = 0; j < 4; ++j)
        acc[i][j] = __builtin_amdgcn_mfma_f32_16x16x32_f16(aF[i], bF[j], acc[i][j], 0, 0, 0);
    __syncthreads();
  }

  // ---------------- epilogue ----------------
  // C layout per 16x16 tile: col = lane&15, row = quad*4 + reg.
  // Pair (ip: a within wave, j: b within wave); t = ih*16 + quad*4 + r, v = colL.
  float msk[16];
#pragma unroll
  for (int ip = 0; ip < 2; ++ip)
#pragma unroll
    for (int ih = 0; ih < 2; ++ih)
#pragma unroll
      for (int r = 0; r < 4; ++r)
        msk[ip * 8 + ih * 4 + r] =
            lmask[(w >> 1) * 64 + (ip * 2 + ih) * 16 + quad * 4 + r];

#pragma unroll
  for (int ip = 0; ip < 2; ++ip) {
#pragma unroll
    for (int j = 0; j < 4; ++j) {
      float x[8];
#pragma unroll
      for (int ih = 0; ih < 2; ++ih)
#pragma unroll
        for (int r = 0; r < 4; ++r)
          x[ih * 4 + r] = acc[ip * 2 + ih][j][r] * msk[ip * 8 + ih * 4 + r];

      // --- level-1 t2v: softmax over v (lanes xor 1,2,4,8), zeros included ---
      float mx[8], se[8], sxe[8];
#pragma unroll
      for (int k = 0; k < 8; ++k) mx[k] = x[k];
#pragma unroll
      for (int d = 1; d < 16; d <<= 1)
#pragma unroll
        for (int k = 0; k < 8; ++k) mx[k] = fmaxf(mx[k], __shfl_xor(mx[k], d));
#pragma unroll
      for (int k = 0; k < 8; ++k) {
        float e = __expf(TAUF * (x[k] - mx[k]));
        se[k] = e; sxe[k] = x[k] * e;
      }
#pragma unroll
      for (int d = 1; d < 16; d <<= 1)
#pragma unroll
        for (int k = 0; k < 8; ++k) {
          se[k]  += __shfl_xor(se[k], d);
          sxe[k] += __shfl_xor(sxe[k], d);
        }
      float t2v_t[8];
#pragma unroll
      for (int k = 0; k < 8; ++k) t2v_t[k] = sxe[k] / se[k];
      // masked rows: x==0 everywhere -> mx=0, se=16, sxe=0 -> t2v_t = 0 exactly.

      // --- level-1 v2t: masked softmax over t (regs + lanes xor 16,32) ---
      float cm = -1e30f;
#pragma unroll
      for (int k = 0; k < 8; ++k) if (x[k] != 0.0f) cm = fmaxf(cm, x[k]);
      cm = fmaxf(cm, __shfl_xor(cm, 16));
      cm = fmaxf(cm, __shfl_xor(cm, 32));
      float cse = 0.f, csxe = 0.f;
#pragma unroll
      for (int k = 0; k < 8; ++k)
        if (x[k] != 0.0f) {
          float e = __expf(TAUF * (x[k] - cm));
          cse += e; csxe += x[k] * e;
        }
      cse  += __shfl_xor(cse, 16);  csxe += __shfl_xor(csxe, 16);
      cse  += __shfl_xor(cse, 32);  csxe += __shfl_xor(csxe, 32);
      const float v2t_v = csxe / cse;   // per column v, replicated over quads

      // --- level-2 t2v: masked softmax over t of t2v_t ---
      float m2 = -1e30f;
#pragma unroll
      for (int k = 0; k < 8; ++k) if (t2v_t[k] != 0.0f) m2 = fmaxf(m2, t2v_t[k]);
      m2 = fmaxf(m2, __shfl_xor(m2, 16));
      m2 = fmaxf(m2, __shfl_xor(m2, 32));
      float s2 = 0.f, sx2 = 0.f;
#pragma unroll
      for (int k = 0; k < 8; ++k)
        if (t2v_t[k] != 0.0f) {
          float e = __expf(TAUF * (t2v_t[k] - m2));
          s2 += e; sx2 += t2v_t[k] * e;
        }
      s2 += __shfl_xor(s2, 16);  sx2 += __shfl_xor(sx2, 16);
      s2 += __shfl_xor(s2, 32);  sx2 += __shfl_xor(sx2, 32);
      const float t2v_ab = sx2 / s2;

      // --- level-2 v2t: softmax over v (no mask) ---
      float m3 = v2t_v;
#pragma unroll
      for (int d = 1; d < 16; d <<= 1) m3 = fmaxf(m3, __shfl_xor(m3, d));
      float e3 = __expf(TAUF * (v2t_v - m3));
      float s3 = e3, sx3 = v2t_v * e3;
#pragma unroll
      for (int d = 1; d < 16; d <<= 1) {
        s3 += __shfl_xor(s3, d);  sx3 += __shfl_xor(sx3, d);
      }
      const float v2t_ab = sx3 / s3;

      if (lane == 0) {
        const int a = bm * 4 + (w >> 1) * 2 + ip;
        const int b = bn * 8 + (w & 1) * 4 + j;
        out[a * B_N + b] = 0.5f * (t2v_ab + v2t_ab);
      }
    }
  }
}

extern "C" void kernel_launch(void* const* d_in, const int* in_sizes, int n_in,
                              void* d_out, int out_size, void* d_ws, size_t ws_size,
                              hipStream_t stream) {
  const float* text  = (const float*)d_in[0];   // [256,32,512] fp32
  const float* video = (const float*)d_in[1];   // [256,16,512] fp32
  const float* tmask = (const float*)d_in[2];   // [256,32] fp32
  float* out = (float*)d_out;                   // [256,256] fp32
  _Float16* H = (_Float16*)d_ws;                // 12288*512 halves = 12.6 MB

  norm_cast_kernel<<<(A_N * T_TOK + B_N * V_FRM) / 4, 256, 0, stream>>>(text, video, H);
  score_kernel<<<dim3(B_N * V_FRM / 128, A_N * T_TOK / 128), 256, 0, stream>>>(H, tmask, out);
}

// Round 2
// 130.104 us; speedup vs baseline: 1.4700x; 1.4700x over previous
//
#include <hip/hip_runtime.h>

#define A_N   256
#define T_TOK 32
#define B_N   256
#define V_FRM 16
#define D_DIM 512
#define K_LOG2E 144.269504089f   // TAU * log2(e), TAU = 100

typedef _Float16 half8 __attribute__((ext_vector_type(8)));
typedef float    floatx4 __attribute__((ext_vector_type(4)));

__device__ __forceinline__ float fast_exp2(float x) {
#if __has_builtin(__builtin_amdgcn_exp2f)
  return __builtin_amdgcn_exp2f(x);
#else
  return exp2f(x);
#endif
}
__device__ __forceinline__ float fast_rcp(float x) {
#if __has_builtin(__builtin_amdgcn_rcpf)
  return __builtin_amdgcn_rcpf(x);
#else
  return 1.0f / x;
#endif
}

// async global->LDS, 16B/lane. LDS dest = wave-uniform base + lane*16.
__device__ __forceinline__ void async_copy16(const void* g, void* l) {
#if __has_builtin(__builtin_amdgcn_global_load_lds)
  __builtin_amdgcn_global_load_lds((const __attribute__((address_space(1))) void*)g,
                                   (__attribute__((address_space(3))) void*)l, 16, 0, 0);
#else
  const int lane = threadIdx.x & 63;
  *(float4*)((char*)l + lane * 16) = *(const float4*)g;
#endif
}

// ---------------- Kernel 1: L2-normalize rows + cast to fp16 ----------------
__global__ __launch_bounds__(256) void norm_cast_kernel(
    const float* __restrict__ text, const float* __restrict__ video,
    _Float16* __restrict__ H)
{
  const int w    = threadIdx.x >> 6;
  const int lane = threadIdx.x & 63;
  const int rid  = blockIdx.x * 4 + w;   // 0..12287
  const float* src = (rid < A_N * T_TOK)
                       ? (text + (size_t)rid * D_DIM)
                       : (video + (size_t)(rid - A_N * T_TOK) * D_DIM);
  float4 v0 = *(const float4*)(src + lane * 8);
  float4 v1 = *(const float4*)(src + lane * 8 + 4);
  float ss = v0.x*v0.x + v0.y*v0.y + v0.z*v0.z + v0.w*v0.w
           + v1.x*v1.x + v1.y*v1.y + v1.z*v1.z + v1.w*v1.w;
#pragma unroll
  for (int d = 1; d < 64; d <<= 1) ss += __shfl_xor(ss, d);
  const float s = 1.0f / fmaxf(sqrtf(ss), 1e-6f);
  half8 hv;
  hv[0] = (_Float16)(v0.x * s); hv[1] = (_Float16)(v0.y * s);
  hv[2] = (_Float16)(v0.z * s); hv[3] = (_Float16)(v0.w * s);
  hv[4] = (_Float16)(v1.x * s); hv[5] = (_Float16)(v1.y * s);
  hv[6] = (_Float16)(v1.z * s); hv[7] = (_Float16)(v1.w * s);
  *(half8*)(H + (size_t)rid * D_DIM + lane * 8) = hv;
}

// ---------------- Kernel 2: fused GEMM + dual softmax pooling ----------------
// Block tile 128x128 (4 a's x 8 b's), 4 waves 2x2, 64x64/wave.
// Epilogue: LDS transpose buffer, serial-row softmaxes (no 16-lane butterflies).
__global__ __launch_bounds__(256, 2) void score_kernel(
    const _Float16* __restrict__ H, const float* __restrict__ tmask,
    float* __restrict__ out)
{
  // LDS: GEMM phase uses sA/sB (16384 B). Epilogue reuses same region as
  // X[8 pairs][32 t][20 f] with pair stride 644 floats (20608 B).
  // LM (mask copy) lives above both at 20608.
  __shared__ __align__(16) char smem[21120];
  _Float16* sA = (_Float16*)smem;
  _Float16* sB = (_Float16*)(smem + 8192);
  float*    X  = (float*)smem;            // pair stride 644 floats (4 mod 32)
  float*    LM = (float*)(smem + 20608);  // [128]

  const int tid  = threadIdx.x;
  const int w    = tid >> 6;
  const int lane = tid & 63;
  const int bn   = blockIdx.x;       // 0..31 -> 8 b's
  const int bm   = blockIdx.y;       // 0..63 -> 4 a's
  const int mBase = bm * 128;
  const int nBase = bn * 128;

  if (tid < 128) LM[tid] = tmask[mBase + tid];

  const char* gA = (const char*)(H + (size_t)mBase * D_DIM);
  const char* gB = (const char*)(H + (size_t)(A_N * T_TOK + nBase) * D_DIM);
  const int rowoff = (lane >> 2) * 1024 + (lane & 3) * 16;

  floatx4 acc[4][4];
#pragma unroll
  for (int i = 0; i < 4; ++i)
#pragma unroll
    for (int j = 0; j < 4; ++j) acc[i][j] = {0.f, 0.f, 0.f, 0.f};

  const int colL = lane & 15;
  const int quad = lane >> 4;
  const int aRowBase = (w >> 1) * 64;
  const int bRowBase = (w & 1) * 64;

  for (int kt = 0; kt < 16; ++kt) {
    const int kb = kt * 64;
#pragma unroll
    for (int is = 0; is < 2; ++is) {
      const int rbase = w * 32 + is * 16;
      async_copy16(gA + (size_t)rbase * 1024 + rowoff + kb, (char*)sA + rbase * 64);
      async_copy16(gB + (size_t)rbase * 1024 + rowoff + kb, (char*)sB + rbase * 64);
    }
    __syncthreads();

    half8 aF[4], bF[4];
#pragma unroll
    for (int i = 0; i < 4; ++i)
      aF[i] = *(const half8*)&sA[(aRowBase + i * 16 + colL) * 32 + quad * 8];
#pragma unroll
    for (int j = 0; j < 4; ++j)
      bF[j] = *(const half8*)&sB[(bRowBase + j * 16 + colL) * 32 + quad * 8];
#pragma unroll
    for (int i = 0; i < 4; ++i)
#pragma unroll
      for (int j = 0; j < 4; ++j)
        acc[i][j] = __builtin_amdgcn_mfma_f32_16x16x32_f16(aF[i], bF[j], acc[i][j], 0, 0, 0);
    __syncthreads();
  }

  // ---- fold text mask into accumulators (masked logits become exact 0) ----
#pragma unroll
  for (int ip = 0; ip < 2; ++ip)
#pragma unroll
    for (int ih = 0; ih < 2; ++ih)
#pragma unroll
      for (int rr = 0; rr < 4; ++rr) {
        const float m = LM[(w >> 1) * 64 + (ip * 2 + ih) * 16 + quad * 4 + rr];
#pragma unroll
        for (int j = 0; j < 4; ++j) acc[ip * 2 + ih][j][rr] *= m;
      }

  // ---- epilogue: 4 rounds of 8 pairs (j = round; pair p = w*2+ip) ----
  const int pG = tid >> 5;          // pair this thread processes (phases A/B)
  const int tA = tid & 31;          // t row (phase A)
  const int vB = (tid >> 1) & 15;   // v column (phase B)
  const int hB = tid & 1;           // t half (phase B)

  for (int rj = 0; rj < 4; ++rj) {
    // write 2 pairs per wave into X[p][t][v]  (t stride 20, pair stride 644)
#pragma unroll
    for (int ip = 0; ip < 2; ++ip) {
      float* basep = X + (w * 2 + ip) * 644 + (quad * 4) * 20 + colL;
#pragma unroll
      for (int ih = 0; ih < 2; ++ih)
#pragma unroll
        for (int rr = 0; rr < 4; ++rr)
          basep[(ih * 16 + rr) * 20] = acc[ip * 2 + ih][rj][rr];
    }
    __syncthreads();

    // ---------- phase A: t2v (serial softmax over v per (pair,t) row) ----------
    const float* rowp = X + pG * 644 + tA * 20;
    float xv[16];
    *(float4*)(&xv[0])  = *(const float4*)(rowp);
    *(float4*)(&xv[4])  = *(const float4*)(rowp + 4);
    *(float4*)(&xv[8])  = *(const float4*)(rowp + 8);
    *(float4*)(&xv[12]) = *(const float4*)(rowp + 12);
    float t8[8];
#pragma unroll
    for (int i = 0; i < 8; ++i) t8[i] = fmaxf(xv[i], xv[i + 8]);
#pragma unroll
    for (int i = 0; i < 4; ++i) t8[i] = fmaxf(t8[i], t8[i + 4]);
    t8[0] = fmaxf(t8[0], t8[2]); t8[1] = fmaxf(t8[1], t8[3]);
    const float mA  = fmaxf(t8[0], t8[1]);
    const float mAK = mA * K_LOG2E;
    float se0 = 0.f, se1 = 0.f, sx0 = 0.f, sx1 = 0.f;
#pragma unroll
    for (int i = 0; i < 16; i += 2) {
      float e0 = fast_exp2(fmaf(xv[i],     K_LOG2E, -mAK));
      float e1 = fast_exp2(fmaf(xv[i + 1], K_LOG2E, -mAK));
      se0 += e0; se1 += e1;
      sx0 = fmaf(xv[i], e0, sx0); sx1 = fmaf(xv[i + 1], e1, sx1);
    }
    const float tv = (sx0 + sx1) * fast_rcp(se0 + se1);  // exact 0 for masked t

    // L2 t2v: masked softmax over 32 t (lanes of the 32-group)
    const float mv = (tv != 0.0f) ? tv : -1e30f;
    float m2 = mv;
#pragma unroll
    for (int d = 1; d < 32; d <<= 1) m2 = fmaxf(m2, __shfl_xor(m2, d));
    const float e2 = fast_exp2(fmaf(mv, K_LOG2E, -m2 * K_LOG2E));
    float s2 = e2, sx2 = mv * e2;    // masked: e2=+0, mv*e2=-0 -> no effect
#pragma unroll
    for (int d = 1; d < 32; d <<= 1) {
      s2 += __shfl_xor(s2, d);  sx2 += __shfl_xor(sx2, d);
    }
    const float t2v_ab = sx2 * fast_rcp(s2);

    // ---------- phase B: v2t (serial masked softmax over t per (pair,v)) ----------
    const float* colp = X + pG * 644 + hB * 320 + vB;
    float mm[16];
#pragma unroll
    for (int i = 0; i < 16; ++i) {
      const float xx = colp[i * 20];
      mm[i] = (xx != 0.0f) ? xx : -1e30f;
    }
    float u8[8];
#pragma unroll
    for (int i = 0; i < 8; ++i) u8[i] = fmaxf(mm[i], mm[i + 8]);
#pragma unroll
    for (int i = 0; i < 4; ++i) u8[i] = fmaxf(u8[i], u8[i + 4]);
    u8[0] = fmaxf(u8[0], u8[2]); u8[1] = fmaxf(u8[1], u8[3]);
    float mB = fmaxf(u8[0], u8[1]);
    mB = fmaxf(mB, __shfl_xor(mB, 1));         // combine the two t-halves
    const float mBK = mB * K_LOG2E;
    float sb0 = 0.f, sb1 = 0.f, xb0 = 0.f, xb1 = 0.f;
#pragma unroll
    for (int i = 0; i < 16; i += 2) {
      float e0 = fast_exp2(fmaf(mm[i],     K_LOG2E, -mBK));  // masked -> +0
      float e1 = fast_exp2(fmaf(mm[i + 1], K_LOG2E, -mBK));
      sb0 += e0; sb1 += e1;
      xb0 = fmaf(mm[i], e0, xb0); xb1 = fmaf(mm[i + 1], e1, xb1);
    }
    float seB = sb0 + sb1, sxB = xb0 + xb1;
    seB += __shfl_xor(seB, 1);  sxB += __shfl_xor(sxB, 1);
    const float v2t_v = sxB * fast_rcp(seB);

    // L2 v2t: softmax over 16 v (lane bits 1..4)
    float m3 = v2t_v;
#pragma unroll
    for (int d = 2; d < 32; d <<= 1) m3 = fmaxf(m3, __shfl_xor(m3, d));
    const float e3 = fast_exp2(fmaf(v2t_v, K_LOG2E, -m3 * K_LOG2E));
    float s3 = e3, sx3 = v2t_v * e3;
#pragma unroll
    for (int d = 2; d < 32; d <<= 1) {
      s3 += __shfl_xor(s3, d);  sx3 += __shfl_xor(sx3, d);
    }
    const float v2t_ab = sx3 * fast_rcp(s3);

    if ((tid & 31) == 0) {
      const int aL = (pG >> 2) * 2 + (pG & 1);
      const int bL = ((pG >> 1) & 1) * 4 + rj;
      out[(bm * 4 + aL) * B_N + bn * 8 + bL] = 0.5f * (t2v_ab + v2t_ab);
    }
    __syncthreads();   // protect X before next round's writes
  }
}

extern "C" void kernel_launch(void* const* d_in, const int* in_sizes, int n_in,
                              void* d_out, int out_size, void* d_ws, size_t ws_size,
                              hipStream_t stream) {
  const float* text  = (const float*)d_in[0];
  const float* video = (const float*)d_in[1];
  const float* tmask = (const float*)d_in[2];
  float* out = (float*)d_out;
  _Float16* H = (_Float16*)d_ws;

  norm_cast_kernel<<<(A_N * T_TOK + B_N * V_FRM) / 4, 256, 0, stream>>>(text, video, H);
  score_kernel<<<dim3(B_N * V_FRM / 128, A_N * T_TOK / 128), 256, 0, stream>>>(H, tmask, out);
}

// Round 3
// 129.659 us; speedup vs baseline: 1.4751x; 1.0034x over previous
//
#include <hip/hip_runtime.h>

#define A_N   256
#define T_TOK 32
#define B_N   256
#define V_FRM 16
#define D_DIM 512
#define K_LOG2E 144.269504089f   // TAU * log2(e), TAU = 100

// Epilogue LDS layout: X[2 rounds][8 pairs][16 v][32 t + 4 pad]
#define TS  36                   // floats per v-row
#define PS  580                  // floats per pair slab (16*36 + 4)
#define REP 4640                 // floats per round slab (8*580)

typedef _Float16 half8 __attribute__((ext_vector_type(8)));
typedef _Float16 half4v __attribute__((ext_vector_type(4)));
typedef float    floatx4 __attribute__((ext_vector_type(4)));

__device__ __forceinline__ float fast_exp2(float x) {
#if __has_builtin(__builtin_amdgcn_exp2f)
  return __builtin_amdgcn_exp2f(x);
#else
  return exp2f(x);
#endif
}
__device__ __forceinline__ float fast_rcp(float x) {
#if __has_builtin(__builtin_amdgcn_rcpf)
  return __builtin_amdgcn_rcpf(x);
#else
  return 1.0f / x;
#endif
}

__device__ __forceinline__ float tree_max16(const float* x) {
  float t[8];
#pragma unroll
  for (int i = 0; i < 8; ++i) t[i] = fmaxf(x[i], x[i + 8]);
#pragma unroll
  for (int i = 0; i < 4; ++i) t[i] = fmaxf(t[i], t[i + 4]);
  t[0] = fmaxf(t[0], t[2]); t[1] = fmaxf(t[1], t[3]);
  return fmaxf(t[0], t[1]);
}
__device__ __forceinline__ void expsum16(const float* x, float mK, float& se, float& sx) {
  float s0 = 0.f, s1 = 0.f, x0 = 0.f, x1 = 0.f;
#pragma unroll
  for (int i = 0; i < 16; i += 2) {
    float e0 = fast_exp2(fmaf(x[i],     K_LOG2E, -mK));
    float e1 = fast_exp2(fmaf(x[i + 1], K_LOG2E, -mK));
    s0 += e0; s1 += e1;
    x0 = fmaf(x[i], e0, x0); x1 = fmaf(x[i + 1], e1, x1);
  }
  se = s0 + s1; sx = x0 + x1;
}

// async global->LDS, 16B/lane. LDS dest = wave-uniform base + lane*16.
__device__ __forceinline__ void async_copy16(const void* g, void* l) {
#if __has_builtin(__builtin_amdgcn_global_load_lds)
  __builtin_amdgcn_global_load_lds((const __attribute__((address_space(1))) void*)g,
                                   (__attribute__((address_space(3))) void*)l, 16, 0, 0);
#else
  const int lane = threadIdx.x & 63;
  *(float4*)((char*)l + lane * 16) = *(const float4*)g;
#endif
}

// ---------------- Kernel 1: L2-normalize rows + cast to fp16 ----------------
// 16-lane group per row, 16 rows per block.
__global__ __launch_bounds__(256) void norm_cast_kernel(
    const float* __restrict__ text, const float* __restrict__ video,
    _Float16* __restrict__ H)
{
  const int g   = threadIdx.x >> 4;
  const int l   = threadIdx.x & 15;
  const int rid = blockIdx.x * 16 + g;   // 0..12287
  const float* src = (rid < A_N * T_TOK)
                       ? (text + (size_t)rid * D_DIM)
                       : (video + (size_t)(rid - A_N * T_TOK) * D_DIM);
  float4 c[8];
#pragma unroll
  for (int k = 0; k < 8; ++k) c[k] = *(const float4*)(src + k * 64 + l * 4);
  float s0 = 0.f, s1 = 0.f;
#pragma unroll
  for (int k = 0; k < 8; k += 2) {
    s0 += c[k].x * c[k].x + c[k].y * c[k].y + c[k].z * c[k].z + c[k].w * c[k].w;
    s1 += c[k+1].x * c[k+1].x + c[k+1].y * c[k+1].y + c[k+1].z * c[k+1].z + c[k+1].w * c[k+1].w;
  }
  float ss = s0 + s1;
#pragma unroll
  for (int d = 1; d < 16; d <<= 1) ss += __shfl_xor(ss, d);
  const float s = 1.0f / fmaxf(sqrtf(ss), 1e-6f);
  _Float16* dst = H + (size_t)rid * D_DIM;
#pragma unroll
  for (int k = 0; k < 8; ++k) {
    half4v h;
    h[0] = (_Float16)(c[k].x * s); h[1] = (_Float16)(c[k].y * s);
    h[2] = (_Float16)(c[k].z * s); h[3] = (_Float16)(c[k].w * s);
    *(half4v*)(dst + k * 64 + l * 4) = h;
  }
}

// ---------------- Kernel 2: fused GEMM + dual softmax pooling ----------------
__global__ __launch_bounds__(256, 2) void score_kernel(
    const _Float16* __restrict__ H, const float* __restrict__ tmask,
    float* __restrict__ out)
{
  // GEMM phase: sA/sB in first 16384 B. Epilogue reuses region as X (37120 B).
  __shared__ __align__(16) char smem[37120 + 512];
  _Float16* sA = (_Float16*)smem;
  _Float16* sB = (_Float16*)(smem + 8192);
  float*    X  = (float*)smem;
  float*    LM = (float*)(smem + 37120);  // [128]

  const int tid  = threadIdx.x;
  const int w    = tid >> 6;
  const int lane = tid & 63;
  const int bn   = blockIdx.x;       // 0..31 -> 8 b's
  const int bm   = blockIdx.y;       // 0..63 -> 4 a's
  const int mBase = bm * 128;
  const int nBase = bn * 128;

  if (tid < 128) LM[tid] = tmask[mBase + tid];

  const char* gA = (const char*)(H + (size_t)mBase * D_DIM);
  const char* gB = (const char*)(H + (size_t)(A_N * T_TOK + nBase) * D_DIM);
  const int rowoff = (lane >> 2) * 1024 + (lane & 3) * 16;

  floatx4 acc[4][4];
#pragma unroll
  for (int i = 0; i < 4; ++i)
#pragma unroll
    for (int j = 0; j < 4; ++j) acc[i][j] = {0.f, 0.f, 0.f, 0.f};

  const int colL = lane & 15;
  const int quad = lane >> 4;
  const int aRowBase = (w >> 1) * 64;
  const int bRowBase = (w & 1) * 64;

  for (int kt = 0; kt < 16; ++kt) {
    const int kb = kt * 64;
#pragma unroll
    for (int is = 0; is < 2; ++is) {
      const int rbase = w * 32 + is * 16;
      async_copy16(gA + (size_t)rbase * 1024 + rowoff + kb, (char*)sA + rbase * 64);
      async_copy16(gB + (size_t)rbase * 1024 + rowoff + kb, (char*)sB + rbase * 64);
    }
    __syncthreads();

    half8 aF[4], bF[4];
#pragma unroll
    for (int i = 0; i < 4; ++i)
      aF[i] = *(const half8*)&sA[(aRowBase + i * 16 + colL) * 32 + quad * 8];
#pragma unroll
    for (int j = 0; j < 4; ++j)
      bF[j] = *(const half8*)&sB[(bRowBase + j * 16 + colL) * 32 + quad * 8];
#pragma unroll
    for (int i = 0; i < 4; ++i)
#pragma unroll
      for (int j = 0; j < 4; ++j)
        acc[i][j] = __builtin_amdgcn_mfma_f32_16x16x32_f16(aF[i], bF[j], acc[i][j], 0, 0, 0);
    __syncthreads();
  }

  // ---- fold text mask into accumulators (masked logits -> exact 0) ----
#pragma unroll
  for (int ip = 0; ip < 2; ++ip)
#pragma unroll
    for (int ih = 0; ih < 2; ++ih)
#pragma unroll
      for (int rr = 0; rr < 4; ++rr) {
        const float m = LM[(w >> 1) * 64 + (ip * 2 + ih) * 16 + quad * 4 + rr];
#pragma unroll
        for (int j = 0; j < 4; ++j) acc[ip * 2 + ih][j][rr] *= m;
      }

  // ---- epilogue: 2 iterations x 2 rounds ----
  const int pG = tid >> 5;          // pair (phases A/B)
  const int tA = tid & 31;          // t row (phase A)
  const int vB = (tid >> 1) & 15;   // v column (phase B)
  const int hB = tid & 1;           // t half (phase B)

  for (int it = 0; it < 2; ++it) {
    const int rjb = it * 2;
    // write 2 rounds: X[rr][p][v][t], t-contiguous float4 per (ip,ih)
#pragma unroll
    for (int rr = 0; rr < 2; ++rr)
#pragma unroll
      for (int ip = 0; ip < 2; ++ip)
#pragma unroll
        for (int ih = 0; ih < 2; ++ih)
          *(floatx4*)(X + rr * REP + (w * 2 + ip) * PS + colL * TS + ih * 16 + quad * 4)
              = acc[ip * 2 + ih][rjb + rr];
    __syncthreads();

    // ---------- phase A: t2v over v, then masked L2 over t ----------
    const float* pa = X + pG * PS + tA;
    float xa[16], xb[16];
#pragma unroll
    for (int v = 0; v < 16; ++v) { xa[v] = pa[v * TS]; xb[v] = pa[REP + v * TS]; }
    float sea, sxa, seb, sxb;
    const float mAa = tree_max16(xa), mAb = tree_max16(xb);
    expsum16(xa, mAa * K_LOG2E, sea, sxa);
    expsum16(xb, mAb * K_LOG2E, seb, sxb);
    const float tva = sxa * fast_rcp(sea);   // exact 0 for masked t
    const float tvb = sxb * fast_rcp(seb);

    float va = (tva != 0.0f) ? tva : -1e30f;
    float vb = (tvb != 0.0f) ? tvb : -1e30f;
    float m2a = va, m2b = vb;
#pragma unroll
    for (int d = 1; d < 32; d <<= 1) {
      m2a = fmaxf(m2a, __shfl_xor(m2a, d));
      m2b = fmaxf(m2b, __shfl_xor(m2b, d));
    }
    float e2a = fast_exp2(fmaf(va, K_LOG2E, -m2a * K_LOG2E));
    float e2b = fast_exp2(fmaf(vb, K_LOG2E, -m2b * K_LOG2E));
    float s2a = e2a, sx2a = va * e2a, s2b = e2b, sx2b = vb * e2b;
#pragma unroll
    for (int d = 1; d < 32; d <<= 1) {
      s2a += __shfl_xor(s2a, d);  sx2a += __shfl_xor(sx2a, d);
      s2b += __shfl_xor(s2b, d);  sx2b += __shfl_xor(sx2b, d);
    }
    const float t2v_a = sx2a * fast_rcp(s2a);
    const float t2v_b = sx2b * fast_rcp(s2b);

    // ---------- phase B: masked v2t over t, then L2 over v ----------
    const float* pb = X + pG * PS + vB * TS + hB * 16;
    float ya[16], yb[16];
#pragma unroll
    for (int j4 = 0; j4 < 4; ++j4) {
      *(float4*)&ya[j4 * 4] = *(const float4*)(pb + j4 * 4);
      *(float4*)&yb[j4 * 4] = *(const float4*)(pb + REP + j4 * 4);
    }
#pragma unroll
    for (int i = 0; i < 16; ++i) {
      ya[i] = (ya[i] != 0.0f) ? ya[i] : -1e30f;
      yb[i] = (yb[i] != 0.0f) ? yb[i] : -1e30f;
    }
    float mBa = tree_max16(ya), mBb = tree_max16(yb);
    mBa = fmaxf(mBa, __shfl_xor(mBa, 1));
    mBb = fmaxf(mBb, __shfl_xor(mBb, 1));
    float seBa, sxBa, seBb, sxBb;
    expsum16(ya, mBa * K_LOG2E, seBa, sxBa);
    expsum16(yb, mBb * K_LOG2E, seBb, sxBb);
    seBa += __shfl_xor(seBa, 1);  sxBa += __shfl_xor(sxBa, 1);
    seBb += __shfl_xor(seBb, 1);  sxBb += __shfl_xor(sxBb, 1);
    const float v2ta = sxBa * fast_rcp(seBa);
    const float v2tb = sxBb * fast_rcp(seBb);

    float m3a = v2ta, m3b = v2tb;
#pragma unroll
    for (int d = 2; d < 32; d <<= 1) {
      m3a = fmaxf(m3a, __shfl_xor(m3a, d));
      m3b = fmaxf(m3b, __shfl_xor(m3b, d));
    }
    float e3a = fast_exp2(fmaf(v2ta, K_LOG2E, -m3a * K_LOG2E));
    float e3b = fast_exp2(fmaf(v2tb, K_LOG2E, -m3b * K_LOG2E));
    float s3a = e3a, sx3a = v2ta * e3a, s3b = e3b, sx3b = v2tb * e3b;
#pragma unroll
    for (int d = 2; d < 32; d <<= 1) {
      s3a += __shfl_xor(s3a, d);  sx3a += __shfl_xor(sx3a, d);
      s3b += __shfl_xor(s3b, d);  sx3b += __shfl_xor(sx3b, d);
    }
    const float v2t_a = sx3a * fast_rcp(s3a);
    const float v2t_b = sx3b * fast_rcp(s3b);

    if ((tid & 31) == 0) {
      const int aL = (pG >> 2) * 2 + (pG & 1);
      const int bL = ((pG >> 1) & 1) * 4 + rjb;
      float* orow = out + (bm * 4 + aL) * B_N + bn * 8;
      orow[bL]     = 0.5f * (t2v_a + v2t_a);
      orow[bL + 1] = 0.5f * (t2v_b + v2t_b);
    }
    if (it == 0) __syncthreads();   // protect X before next iteration's writes
  }
}

extern "C" void kernel_launch(void* const* d_in, const int* in_sizes, int n_in,
                              void* d_out, int out_size, void* d_ws, size_t ws_size,
                              hipStream_t stream) {
  const float* text  = (const float*)d_in[0];
  const float* video = (const float*)d_in[1];
  const float* tmask = (const float*)d_in[2];
  float* out = (float*)d_out;
  _Float16* H = (_Float16*)d_ws;

  norm_cast_kernel<<<(A_N * T_TOK + B_N * V_FRM) / 16, 256, 0, stream>>>(text, video, H);
  score_kernel<<<dim3(B_N * V_FRM / 128, A_N * T_TOK / 128), 256, 0, stream>>>(H, tmask, out);
}